// Round 1
// baseline (544.541 us; speedup 1.0000x reference)
//
#include <hip/hip_runtime.h>
#include <hip/hip_bf16.h>

#define C 128
#define RBFD 20
#define NATOMS 50000

// ---------------------------------------------------------------------------
// Kernel 1: transpose W1, W2 (C x C, row-major [out][in]) into [in][out]
// so the MLP GEMM's B-loads are coalesced.
// ---------------------------------------------------------------------------
__global__ void transpose_w_kernel(const float* __restrict__ W1,
                                   const float* __restrict__ W2,
                                   float* __restrict__ W1T,
                                   float* __restrict__ W2T) {
    int t = blockIdx.x * blockDim.x + threadIdx.x;
    if (t < C * C) {
        int k = t / C;   // in-channel
        int c = t % C;   // out-channel
        W1T[t] = W1[c * C + k];
        W2T[t] = W2[c * C + k];
    }
}

// ---------------------------------------------------------------------------
// Kernel 2: per-edge filter + scatter-add into acc[N][C].
// 128 threads per edge (2 waves); thread's channel c is fixed across the
// grid-stride loop so the W_rbf row lives in 20 VGPRs.
// rbf/env/idx loads are wave-uniform (cache broadcast); x load is coalesced.
// ---------------------------------------------------------------------------
__global__ __launch_bounds__(256) void edge_scatter_kernel(
    const float* __restrict__ x,       // [E][C]
    const float* __restrict__ rbf,     // [E][RBFD]
    const float* __restrict__ env,     // [E]
    const int*   __restrict__ idx,     // [E]
    const float* __restrict__ Wrbf,    // [C][RBFD]
    const float* __restrict__ brbf,    // [C]
    float* __restrict__ acc,           // [N][C]
    int E)
{
    const int tid = blockIdx.x * blockDim.x + threadIdx.x;
    const int c = tid & (C - 1);
    const int nthreads = gridDim.x * blockDim.x;
    const int edges_per_iter = nthreads >> 7;   // threads / 128

    // W_rbf row for this thread's channel, kept in registers.
    float w[RBFD];
#pragma unroll
    for (int r = 0; r < RBFD; ++r) w[r] = Wrbf[c * RBFD + r];
    const float bias = brbf[c];

    for (int e = tid >> 7; e < E; e += edges_per_iter) {
        // 20 floats of rbf row via 5 float4 loads (80B, 16B-aligned since 80%16==0)
        const float4* r4 = reinterpret_cast<const float4*>(rbf + (size_t)e * RBFD);
        float4 rv0 = r4[0], rv1 = r4[1], rv2 = r4[2], rv3 = r4[3], rv4 = r4[4];

        float f = bias;
        f = fmaf(rv0.x, w[0], f);  f = fmaf(rv0.y, w[1], f);
        f = fmaf(rv0.z, w[2], f);  f = fmaf(rv0.w, w[3], f);
        f = fmaf(rv1.x, w[4], f);  f = fmaf(rv1.y, w[5], f);
        f = fmaf(rv1.z, w[6], f);  f = fmaf(rv1.w, w[7], f);
        f = fmaf(rv2.x, w[8], f);  f = fmaf(rv2.y, w[9], f);
        f = fmaf(rv2.z, w[10], f); f = fmaf(rv2.w, w[11], f);
        f = fmaf(rv3.x, w[12], f); f = fmaf(rv3.y, w[13], f);
        f = fmaf(rv3.z, w[14], f); f = fmaf(rv3.w, w[15], f);
        f = fmaf(rv4.x, w[16], f); f = fmaf(rv4.y, w[17], f);
        f = fmaf(rv4.z, w[18], f); f = fmaf(rv4.w, w[19], f);

        const float fe  = f * env[e];
        const float val = fe * x[(size_t)e * C + c];
        const int   a   = idx[e];
        unsafeAtomicAdd(acc + (size_t)a * C + c, val);
    }
}

// ---------------------------------------------------------------------------
// Kernel 3: fused MLP head.  One block per 128-atom tile, 256 threads as a
// 16x16 grid of 8x8 register tiles.  h tile staged in LDS [k][atom] with +1
// padding (conflict-free loads AND stores).  W1T/W2T streamed from L2.
// layer1 -> silu -> (LDS) -> layer2 -> silu -> dot with W3 -> out[N].
// ---------------------------------------------------------------------------
__device__ __forceinline__ float silu_f(float v) {
    return v * (1.0f / (1.0f + __expf(-v)));
}

__global__ __launch_bounds__(256) void mlp_head_kernel(
    const float* __restrict__ acc,   // [N][C]
    const float* __restrict__ W1T,   // [C][C]  (k-major)
    const float* __restrict__ b1,    // [C]
    const float* __restrict__ W2T,   // [C][C]
    const float* __restrict__ b2,    // [C]
    const float* __restrict__ W3,    // [1][C]
    const float* __restrict__ b3,    // [1]
    float* __restrict__ out,         // [N]
    int natoms)
{
    __shared__ float As[C][C + 1];   // 66 KB, [k][atom] with padding

    const int tid = threadIdx.x;
    const int a0  = blockIdx.x * C;
    const int tc  = tid & 15;        // output-col tile
    const int ta  = tid >> 4;        // atom tile
    const int abase = ta * 8;
    const int cbase = tc * 8;

    // ---- load h tile: 2 atoms x 128 k per pass, coalesced global reads ----
    {
        const int sub = tid >> 7;        // 0 or 1
        const int k   = tid & 127;
        for (int pair = 0; pair < 64; ++pair) {
            const int al = pair * 2 + sub;       // local atom 0..127
            const int a  = a0 + al;
            float v = (a < natoms) ? acc[(size_t)a * C + k] : 0.0f;
            As[k][al] = v;                        // bank = (k + al) % 32: conflict-free
        }
    }
    __syncthreads();

    float r[8][8];

    // ---------------- layer 1 ----------------
#pragma unroll
    for (int i = 0; i < 8; ++i)
#pragma unroll
        for (int j = 0; j < 8; ++j) r[i][j] = 0.0f;

#pragma unroll 2
    for (int k = 0; k < C; ++k) {
        float4 bq0 = *reinterpret_cast<const float4*>(W1T + k * C + cbase);
        float4 bq1 = *reinterpret_cast<const float4*>(W1T + k * C + cbase + 4);
        float bv[8] = {bq0.x, bq0.y, bq0.z, bq0.w, bq1.x, bq1.y, bq1.z, bq1.w};
        float av[8];
#pragma unroll
        for (int i = 0; i < 8; ++i) av[i] = As[k][abase + i];
#pragma unroll
        for (int i = 0; i < 8; ++i)
#pragma unroll
            for (int j = 0; j < 8; ++j) r[i][j] = fmaf(av[i], bv[j], r[i][j]);
    }

    __syncthreads();   // all reads of As done
    // silu(.. + b1) -> back into As as [k'=c][atom]
    {
        float bb[8];
#pragma unroll
        for (int j = 0; j < 8; ++j) bb[j] = b1[cbase + j];
#pragma unroll
        for (int i = 0; i < 8; ++i)
#pragma unroll
            for (int j = 0; j < 8; ++j)
                As[cbase + j][abase + i] = silu_f(r[i][j] + bb[j]);
    }
    __syncthreads();

    // ---------------- layer 2 ----------------
#pragma unroll
    for (int i = 0; i < 8; ++i)
#pragma unroll
        for (int j = 0; j < 8; ++j) r[i][j] = 0.0f;

#pragma unroll 2
    for (int k = 0; k < C; ++k) {
        float4 bq0 = *reinterpret_cast<const float4*>(W2T + k * C + cbase);
        float4 bq1 = *reinterpret_cast<const float4*>(W2T + k * C + cbase + 4);
        float bv[8] = {bq0.x, bq0.y, bq0.z, bq0.w, bq1.x, bq1.y, bq1.z, bq1.w};
        float av[8];
#pragma unroll
        for (int i = 0; i < 8; ++i) av[i] = As[k][abase + i];
#pragma unroll
        for (int i = 0; i < 8; ++i)
#pragma unroll
            for (int j = 0; j < 8; ++j) r[i][j] = fmaf(av[i], bv[j], r[i][j]);
    }

    __syncthreads();   // all reads of As done before reuse as reduce scratch

    // ---------------- final: silu(.. + b2) . W3 ----------------
    {
        float bb[8], w3v[8];
#pragma unroll
        for (int j = 0; j < 8; ++j) bb[j] = b2[cbase + j];
        float4 wq0 = *reinterpret_cast<const float4*>(W3 + cbase);
        float4 wq1 = *reinterpret_cast<const float4*>(W3 + cbase + 4);
        w3v[0]=wq0.x; w3v[1]=wq0.y; w3v[2]=wq0.z; w3v[3]=wq0.w;
        w3v[4]=wq1.x; w3v[5]=wq1.y; w3v[6]=wq1.z; w3v[7]=wq1.w;

#pragma unroll
        for (int i = 0; i < 8; ++i) {
            float p = 0.0f;
#pragma unroll
            for (int j = 0; j < 8; ++j)
                p = fmaf(silu_f(r[i][j] + bb[j]), w3v[j], p);
            As[abase + i][tc] = p;   // partial per (atom, col-tile)
        }
    }
    __syncthreads();

    if (tid < C) {
        const int a = a0 + tid;
        if (a < natoms) {
            float s = 0.0f;
#pragma unroll
            for (int t = 0; t < 16; ++t) s += As[tid][t];
            out[a] = s + b3[0];
        }
    }
}

// ---------------------------------------------------------------------------
extern "C" void kernel_launch(void* const* d_in, const int* in_sizes, int n_in,
                              void* d_out, int out_size, void* d_ws, size_t ws_size,
                              hipStream_t stream) {
    const float* x      = (const float*)d_in[0];
    const float* rbf    = (const float*)d_in[1];
    const float* env    = (const float*)d_in[2];
    const int*   idx    = (const int*)  d_in[3];
    // d_in[4] = num_atoms (device scalar; shapes are fixed by the problem)
    const float* Wrbf   = (const float*)d_in[5];
    const float* brbf   = (const float*)d_in[6];
    const float* W1     = (const float*)d_in[7];
    const float* b1     = (const float*)d_in[8];
    const float* W2     = (const float*)d_in[9];
    const float* b2     = (const float*)d_in[10];
    const float* W3     = (const float*)d_in[11];
    const float* b3     = (const float*)d_in[12];
    float*       out    = (float*)d_out;

    const int E = in_sizes[0] / C;        // 800000
    const int N = NATOMS;                 // 50000

    // workspace layout
    float* acc = (float*)d_ws;                       // N*C floats = 25.6 MB
    float* W1T = acc + (size_t)N * C;                // C*C
    float* W2T = W1T + C * C;                        // C*C

    // zero the accumulator
    hipMemsetAsync(acc, 0, (size_t)N * C * sizeof(float), stream);

    // transpose weights
    transpose_w_kernel<<<(C * C + 255) / 256, 256, 0, stream>>>(W1, W2, W1T, W2T);

    // edge scatter: 2048 blocks x 256 threads = full occupancy grid-stride
    edge_scatter_kernel<<<2048, 256, 0, stream>>>(x, rbf, env, idx, Wrbf, brbf, acc, E);

    // MLP head: one block per 128-atom tile
    const int tiles = (N + C - 1) / C;
    mlp_head_kernel<<<tiles, 256, 0, stream>>>(acc, W1T, b1, W2T, b2, W3, b3, out, N);
}